// Round 11
// baseline (195.548 us; speedup 1.0000x reference)
//
#include <hip/hip_runtime.h>
#include <hip/hip_bf16.h>

#define NROWS 8192
#define KD    1024

typedef __attribute__((ext_vector_type(8))) short bf16x8;
typedef __attribute__((ext_vector_type(4))) float f32x4;

__device__ unsigned short g_x1n[(size_t)NROWS * KD];
__device__ unsigned short g_x2n[(size_t)NROWS * KD];

__device__ __forceinline__ unsigned short f2bf(float f) {
    union { float f; unsigned u; } x; x.f = f;
    return (unsigned short)((x.u + 0x7fffu + ((x.u >> 16) & 1u)) >> 16);  // RNE
}

__global__ __launch_bounds__(256) void norm_cast_kernel(const float* __restrict__ x1,
                                                        const float* __restrict__ x2) {
    int row = blockIdx.x;
    const float* src;
    unsigned short* dst;
    if (row < NROWS) { src = x1 + (size_t)row * KD;           dst = g_x1n + (size_t)row * KD; }
    else             { src = x2 + (size_t)(row - NROWS) * KD; dst = g_x2n + (size_t)(row - NROWS) * KD; }

    int t = threadIdx.x;
    float4 v = ((const float4*)src)[t];
    float s = v.x * v.x + v.y * v.y + v.z * v.z + v.w * v.w;
    #pragma unroll
    for (int off = 32; off > 0; off >>= 1) s += __shfl_down(s, off);

    __shared__ float red[4];
    if ((t & 63) == 0) red[t >> 6] = s;
    __syncthreads();
    float tot = red[0] + red[1] + red[2] + red[3];
    float inv = 1.0f / fmaxf(sqrtf(tot), 1e-8f);

    ushort4 o;
    o.x = f2bf(v.x * inv); o.y = f2bf(v.y * inv);
    o.z = f2bf(v.z * inv); o.w = f2bf(v.w * inv);
    ((ushort4*)dst)[t] = o;
}

__device__ __forceinline__ void gload_lds16(const unsigned short* g, unsigned short* l) {
    __builtin_amdgcn_global_load_lds((const __attribute__((address_space(1))) void*)g,
                                     (__attribute__((address_space(3))) void*)l,
                                     16, 0, 0);
}

#define BARX() do { asm volatile("" ::: "memory"); __builtin_amdgcn_s_barrier(); \
                    asm volatile("" ::: "memory"); } while (0)
#define DRAIN_LDS() do { asm volatile("s_waitcnt lgkmcnt(0)" ::: "memory"); \
                         __builtin_amdgcn_sched_barrier(0); } while (0)
#define MFMA16(a, b, c) __builtin_amdgcn_mfma_f32_16x16x32_bf16((a), (b), (c), 0, 0, 0)

struct Ctx {
    const unsigned short* Ablk;
    const unsigned short* Bblk;
    unsigned short* ldsf;
    int ldst;                     // t*8 (stage dest elem offset within region)
    int trow;                     // t>>3 (staging row 0..127)
    int scol;                     // pre-swizzled source col element offset
    int s0, s1;                   // swizzled 16B-slot byte-elem offsets (kk=0/1)
    int arbase, brbase;           // row-base elem offsets within region
    int areg, breg;               // region indices (0/1 and 2/3)
};

// Stage one half-tile (128 rows x 64 k): ONE global_load_lds(16B) per thread (1024 thr).
__device__ __forceinline__ void stage_half(const Ctx& c, const unsigned short* mat,
                                           int hbit, int region, int Tk) {
    const unsigned short* src = mat + (size_t)(hbit * 128 + c.trow) * KD + Tk * 64 + c.scol;
    gload_lds16(src, c.ldsf + region * 8192 + c.ldst);
}

// One K-tile (BK=64), 16 waves: 2 phases (kk-halves), 16 MFMA each.
// ph0 stages (T+1).A0,A1 ; ph1 stages (T+2).B0,B1 ; counted vmcnt(2).
template<int BUF, bool SA, bool SB, int WAITN>
__device__ __forceinline__ void tile_body(const Ctx& c, f32x4 (&acc)[4][4], int T) {
    const unsigned short* ar = c.ldsf + (BUF * 4 + c.areg) * 8192 + c.arbase;
    const unsigned short* br = c.ldsf + (BUF * 4 + c.breg) * 8192 + c.brbase;
    bf16x8 A[4], B[4][2];

    // ---- ph0: read A kk0 (4) + B kk0,kk1 (8); stage (T+1).A; MFMA kk0 ----
    #pragma unroll
    for (int mi = 0; mi < 4; ++mi)
        A[mi] = *(const bf16x8*)(ar + mi * 1024 + c.s0);
    #pragma unroll
    for (int ni = 0; ni < 4; ++ni) {
        B[ni][0] = *(const bf16x8*)(br + ni * 1024 + c.s0);
        B[ni][1] = *(const bf16x8*)(br + ni * 1024 + c.s1);
    }
    if (SA) {
        stage_half(c, c.Ablk, 0, (BUF ^ 1) * 4 + 0, T + 1);
        stage_half(c, c.Ablk, 1, (BUF ^ 1) * 4 + 1, T + 1);
    }
    asm volatile("s_waitcnt lgkmcnt(8)" ::: "memory");   // 12-read phase pacing hint
    BARX();
    DRAIN_LDS();
    __builtin_amdgcn_s_setprio(1);
    #pragma unroll
    for (int mi = 0; mi < 4; ++mi)
        #pragma unroll
        for (int ni = 0; ni < 4; ++ni)
            acc[mi][ni] = MFMA16(A[mi], B[ni][0], acc[mi][ni]);
    __builtin_amdgcn_s_setprio(0);
    BARX();   // all B(T) reads complete before this point -> (T+2).B stage below is safe

    // ---- ph1: read A kk1 (4); stage (T+2).B; MFMA kk1 ----
    #pragma unroll
    for (int mi = 0; mi < 4; ++mi)
        A[mi] = *(const bf16x8*)(ar + mi * 1024 + c.s1);
    if (SB) {
        stage_half(c, c.Bblk, 0, BUF * 4 + 2, T + 2);
        stage_half(c, c.Bblk, 1, BUF * 4 + 3, T + 2);
    }
    BARX();
    DRAIN_LDS();
    __builtin_amdgcn_s_setprio(1);
    #pragma unroll
    for (int mi = 0; mi < 4; ++mi)
        #pragma unroll
        for (int ni = 0; ni < 4; ++ni)
            acc[mi][ni] = MFMA16(A[mi], B[ni][1], acc[mi][ni]);
    __builtin_amdgcn_s_setprio(0);
    if (WAITN == 2)      asm volatile("s_waitcnt vmcnt(2)" ::: "memory");
    else if (WAITN == 0) asm volatile("s_waitcnt vmcnt(0)" ::: "memory");
    BARX();
}

// 256x256 tile, BK=64, 16 waves (4M x 4N, 1024 thr): 4 waves/SIMD for pipe overlap.
__global__ __launch_bounds__(1024, 4) void gemm16_kernel(float* __restrict__ C) {
    __shared__ unsigned short lds[2][4][8192];   // 128 KiB

    // L2-rectangle XCD mapping (bijective), bn-band pinned per XCD (round 5: FETCH -63%).
    int bid = blockIdx.x;                 // 1024 blocks
    int xcd  = bid & 7;
    int idx  = bid >> 3;
    int rnd  = idx >> 5;
    int j    = idx & 31;
    int rect = rnd * 8 + xcd;
    int bm = (rect >> 2) * 4 + (j >> 3);
    int bn = (rect & 3) * 8 + (j & 7);

    int t = threadIdx.x;
    int lane = t & 63, wid = t >> 6;      // wid 0..15
    int wr = wid >> 2, wc = wid & 3;      // 4x4 wave grid, each 64x64 output
    int r = lane & 15;
    int kq = lane >> 4;                   // 0..3

    Ctx c;
    c.Ablk = g_x1n + (size_t)bm * 256 * KD;
    c.Bblk = g_x2n + (size_t)bn * 256 * KD;
    c.ldsf = &lds[0][0][0];
    c.ldst = t * 8;
    c.trow = t >> 3;                      // 0..127
    c.scol = ((t & 7) ^ ((t >> 3) & 7)) * 8;      // inverse swizzle on global source
    c.s0 = (kq ^ (r & 7)) * 8;            // kk=0 swizzled slot
    c.s1 = ((kq ^ 4) ^ (r & 7)) * 8;      // kk=1 (slot 4+kq == kq^4)
    c.arbase = ((wr & 1) * 64 + r) * 64;
    c.brbase = ((wc & 1) * 64 + r) * 64;
    c.areg = wr >> 1;
    c.breg = 2 + (wc >> 1);

    f32x4 acc[4][4] = {};

    // Prologue: stage A(0)->[0,1], B(0)->[2,3], B(1)->[6,7]; wait tile0 (leave B1).
    stage_half(c, c.Ablk, 0, 0, 0);
    stage_half(c, c.Ablk, 1, 1, 0);
    stage_half(c, c.Bblk, 0, 2, 0);
    stage_half(c, c.Bblk, 1, 3, 0);
    stage_half(c, c.Bblk, 0, 6, 1);
    stage_half(c, c.Bblk, 1, 7, 1);
    asm volatile("s_waitcnt vmcnt(2)" ::: "memory");
    BARX();

    for (int it = 0; it < 7; ++it) {      // tiles 0..13, full staging
        tile_body<0, true, true, 2>(c, acc, 2 * it);
        tile_body<1, true, true, 2>(c, acc, 2 * it + 1);
    }
    tile_body<0, true, false, 0>(c, acc, 14);   // stages (15).A, drains
    tile_body<1, false, false, -1>(c, acc, 15);

    // Epilogue: C/D layout col = lane&15, row = (lane>>4)*4 + j.
    int cn = lane & 15, rq = (lane >> 4) * 4;
    int rbase = bm * 256 + wr * 64;
    int cbase = bn * 256 + wc * 64;
    #pragma unroll
    for (int mi = 0; mi < 4; ++mi)
        #pragma unroll
        for (int ni = 0; ni < 4; ++ni)
            #pragma unroll
            for (int j2 = 0; j2 < 4; ++j2)
                C[(size_t)(rbase + mi * 16 + rq + j2) * NROWS + cbase + ni * 16 + cn] =
                    acc[mi][ni][j2] * 20.0f;
}

extern "C" void kernel_launch(void* const* d_in, const int* in_sizes, int n_in,
                              void* d_out, int out_size, void* d_ws, size_t ws_size,
                              hipStream_t stream) {
    (void)in_sizes; (void)n_in; (void)d_ws; (void)ws_size; (void)out_size;
    const float* x1 = (const float*)d_in[0];
    const float* x2 = (const float*)d_in[1];
    float* out = (float*)d_out;

    norm_cast_kernel<<<2 * NROWS, 256, 0, stream>>>(x1, x2);
    gemm16_kernel<<<(NROWS / 256) * (NROWS / 256), 1024, 0, stream>>>(out);
}